// Round 1
// baseline (61.140 us; speedup 1.0000x reference)
//
#include <hip/hip_runtime.h>
#include <math.h>

#define N_PTS 4194304
#define M_CAM 2048

// Packed per-camera record: 4 x float4 = 64 B
//   c0 = (R00, R01, R02, t0)
//   c1 = (R10, R11, R12, t1)
//   c2 = (R20, R21, R22, t2)
//   c3 = (fx, fy, cx, cy)

__global__ void cam_precompute(const float* __restrict__ intr,
                               const float* __restrict__ Rn,
                               const float* __restrict__ tn,
                               const float* __restrict__ intr_d,
                               const float* __restrict__ rot_d,
                               const float* __restrict__ trans_d,
                               float4* __restrict__ cam) {
    int m = blockIdx.x * blockDim.x + threadIdx.x;
    if (m >= M_CAM) return;

    float rx = rot_d[3 * m + 0];
    float ry = rot_d[3 * m + 1];
    float rz = rot_d[3 * m + 2];
    float theta = sqrtf(rx * rx + ry * ry + rz * rz);
    float inv = 1.0f / fmaxf(theta, 1e-12f);
    float kx = rx * inv, ky = ry * inv, kz = rz * inv;
    float st = sinf(theta);
    float ct = cosf(theta);
    float omc = 1.0f - ct;

    // R_delta = I + st*K + (1-ct)*K^2 with K = [[0,-kz,ky],[kz,0,-kx],[-ky,kx,0]]
    float Rd[9];
    Rd[0] = 1.0f - omc * (ky * ky + kz * kz);
    Rd[1] = -st * kz + omc * (kx * ky);
    Rd[2] =  st * ky + omc * (kx * kz);
    Rd[3] =  st * kz + omc * (kx * ky);
    Rd[4] = 1.0f - omc * (kx * kx + kz * kz);
    Rd[5] = -st * kx + omc * (ky * kz);
    Rd[6] = -st * ky + omc * (kx * kz);
    Rd[7] =  st * kx + omc * (ky * kz);
    Rd[8] = 1.0f - omc * (kx * kx + ky * ky);

    // R_corr = R_delta @ R_noisy
    float Rm[9];
#pragma unroll
    for (int i = 0; i < 3; ++i) {
#pragma unroll
        for (int j = 0; j < 3; ++j) {
            Rm[3 * i + j] = Rd[3 * i + 0] * Rn[9 * m + 0 + j]
                          + Rd[3 * i + 1] * Rn[9 * m + 3 + j]
                          + Rd[3 * i + 2] * Rn[9 * m + 6 + j];
        }
    }

    float t0 = tn[3 * m + 0] + trans_d[3 * m + 0];
    float t1 = tn[3 * m + 1] + trans_d[3 * m + 1];
    float t2 = tn[3 * m + 2] + trans_d[3 * m + 2];

    float k0 = intr[4 * m + 0] + intr_d[4 * m + 0];
    float k1 = intr[4 * m + 1] + intr_d[4 * m + 1];
    float k2 = intr[4 * m + 2] + intr_d[4 * m + 2];
    float k3 = intr[4 * m + 3] + intr_d[4 * m + 3];

    cam[4 * m + 0] = make_float4(Rm[0], Rm[1], Rm[2], t0);
    cam[4 * m + 1] = make_float4(Rm[3], Rm[4], Rm[5], t1);
    cam[4 * m + 2] = make_float4(Rm[6], Rm[7], Rm[8], t2);
    cam[4 * m + 3] = make_float4(k0, k1, k2, k3);
}

__device__ __forceinline__ float2 project_one(const float4* __restrict__ cam,
                                              int c, float px, float py, float pz) {
    float4 r0 = cam[4 * c + 0];
    float4 r1 = cam[4 * c + 1];
    float4 r2 = cam[4 * c + 2];
    float4 kk = cam[4 * c + 3];
    float xc = fmaf(r0.x, px, fmaf(r0.y, py, fmaf(r0.z, pz, r0.w)));
    float yc = fmaf(r1.x, px, fmaf(r1.y, py, fmaf(r1.z, pz, r1.w)));
    float zc = fmaf(r2.x, px, fmaf(r2.y, py, fmaf(r2.z, pz, r2.w)));
    float iz = 1.0f / zc;
    float u = (kk.x * xc) * iz + kk.z;
    float v = (kk.y * yc) * iz + kk.w;
    return make_float2(u, v);
}

__global__ void project_points(const float* __restrict__ X,
                               const int* __restrict__ idx,
                               const float4* __restrict__ cam,
                               float* __restrict__ out) {
    const int n_groups = N_PTS / 4;            // each thread-iteration handles 4 points
    const int stride = gridDim.x * blockDim.x;
    const float4* __restrict__ X4 = (const float4*)X;
    const int4* __restrict__ I4 = (const int4*)idx;
    float4* __restrict__ O4 = (float4*)out;

    for (int t = blockIdx.x * blockDim.x + threadIdx.x; t < n_groups; t += stride) {
        float4 a = X4[3 * t + 0];  // p0.x p0.y p0.z p1.x
        float4 b = X4[3 * t + 1];  // p1.y p1.z p2.x p2.y
        float4 c = X4[3 * t + 2];  // p2.z p3.x p3.y p3.z
        int4 ci = I4[t];

        float2 uv0 = project_one(cam, ci.x, a.x, a.y, a.z);
        float2 uv1 = project_one(cam, ci.y, a.w, b.x, b.y);
        float2 uv2 = project_one(cam, ci.z, b.z, b.w, c.x);
        float2 uv3 = project_one(cam, ci.w, c.y, c.z, c.w);

        O4[2 * t + 0] = make_float4(uv0.x, uv0.y, uv1.x, uv1.y);
        O4[2 * t + 1] = make_float4(uv2.x, uv2.y, uv3.x, uv3.y);
    }
}

extern "C" void kernel_launch(void* const* d_in, const int* in_sizes, int n_in,
                              void* d_out, int out_size, void* d_ws, size_t ws_size,
                              hipStream_t stream) {
    const float* X_world      = (const float*)d_in[0];
    const int*   cam_idx      = (const int*)d_in[1];
    const float* intrinsics   = (const float*)d_in[2];
    const float* R_noisy      = (const float*)d_in[3];
    const float* t_noisy      = (const float*)d_in[4];
    const float* intr_deltas  = (const float*)d_in[5];
    const float* rot_deltas   = (const float*)d_in[6];
    const float* trans_deltas = (const float*)d_in[7];
    float* out = (float*)d_out;
    float4* cam = (float4*)d_ws;   // 2048 * 64 B = 128 KB

    cam_precompute<<<(M_CAM + 255) / 256, 256, 0, stream>>>(
        intrinsics, R_noisy, t_noisy, intr_deltas, rot_deltas, trans_deltas, cam);

    project_points<<<2048, 256, 0, stream>>>(X_world, cam_idx, cam, out);
}

// Round 2
// 28.260 us; speedup vs baseline: 2.1635x; 2.1635x over previous
//
#include <hip/hip_runtime.h>
#include <math.h>

#define N_PTS 4194304
#define M_CAM 2048
#define NG (N_PTS / 4)

// SoA camera table, one float4 per "row" r of the packed record:
//   cam[0*M + m] = (R00, R01, R02, t0)
//   cam[1*M + m] = (R10, R11, R12, t1)
//   cam[2*M + m] = (R20, R21, R22, t2)
//   cam[3*M + m] = (fx, fy, cx, cy)

__global__ void cam_precompute(const float* __restrict__ intr,
                               const float* __restrict__ Rn,
                               const float* __restrict__ tn,
                               const float* __restrict__ intr_d,
                               const float* __restrict__ rot_d,
                               const float* __restrict__ trans_d,
                               float4* __restrict__ cam) {
    int m = blockIdx.x * blockDim.x + threadIdx.x;
    if (m >= M_CAM) return;

    float rx = rot_d[3 * m + 0];
    float ry = rot_d[3 * m + 1];
    float rz = rot_d[3 * m + 2];
    float theta = sqrtf(rx * rx + ry * ry + rz * rz);
    float inv = 1.0f / fmaxf(theta, 1e-12f);
    float kx = rx * inv, ky = ry * inv, kz = rz * inv;
    float st = sinf(theta);
    float ct = cosf(theta);
    float omc = 1.0f - ct;

    // R_delta = I + st*K + (1-ct)*K^2, K = [[0,-kz,ky],[kz,0,-kx],[-ky,kx,0]]
    float Rd[9];
    Rd[0] = 1.0f - omc * (ky * ky + kz * kz);
    Rd[1] = -st * kz + omc * (kx * ky);
    Rd[2] =  st * ky + omc * (kx * kz);
    Rd[3] =  st * kz + omc * (kx * ky);
    Rd[4] = 1.0f - omc * (kx * kx + kz * kz);
    Rd[5] = -st * kx + omc * (ky * kz);
    Rd[6] = -st * ky + omc * (kx * kz);
    Rd[7] =  st * kx + omc * (ky * kz);
    Rd[8] = 1.0f - omc * (kx * kx + ky * ky);

    // R_corr = R_delta @ R_noisy
    float Rm[9];
#pragma unroll
    for (int i = 0; i < 3; ++i) {
#pragma unroll
        for (int j = 0; j < 3; ++j) {
            Rm[3 * i + j] = Rd[3 * i + 0] * Rn[9 * m + 0 + j]
                          + Rd[3 * i + 1] * Rn[9 * m + 3 + j]
                          + Rd[3 * i + 2] * Rn[9 * m + 6 + j];
        }
    }

    float t0 = tn[3 * m + 0] + trans_d[3 * m + 0];
    float t1 = tn[3 * m + 1] + trans_d[3 * m + 1];
    float t2 = tn[3 * m + 2] + trans_d[3 * m + 2];

    cam[0 * M_CAM + m] = make_float4(Rm[0], Rm[1], Rm[2], t0);
    cam[1 * M_CAM + m] = make_float4(Rm[3], Rm[4], Rm[5], t1);
    cam[2 * M_CAM + m] = make_float4(Rm[6], Rm[7], Rm[8], t2);
    cam[3 * M_CAM + m] = make_float4(intr[4 * m + 0] + intr_d[4 * m + 0],
                                     intr[4 * m + 1] + intr_d[4 * m + 1],
                                     intr[4 * m + 2] + intr_d[4 * m + 2],
                                     intr[4 * m + 3] + intr_d[4 * m + 3]);
}

__device__ __forceinline__ float2 project_one(const float4* __restrict__ lds,
                                              int c, float px, float py, float pz) {
    float4 r0 = lds[0 * M_CAM + c];
    float4 r1 = lds[1 * M_CAM + c];
    float4 r2 = lds[2 * M_CAM + c];
    float4 kk = lds[3 * M_CAM + c];
    float xc = fmaf(r0.x, px, fmaf(r0.y, py, fmaf(r0.z, pz, r0.w)));
    float yc = fmaf(r1.x, px, fmaf(r1.y, py, fmaf(r1.z, pz, r1.w)));
    float zc = fmaf(r2.x, px, fmaf(r2.y, py, fmaf(r2.z, pz, r2.w)));
    float iz = 1.0f / zc;
    float u = (kk.x * xc) * iz + kk.z;
    float v = (kk.y * yc) * iz + kk.w;
    return make_float2(u, v);
}

__global__ __launch_bounds__(1024) void project_points(const float* __restrict__ X,
                                                       const int* __restrict__ idx,
                                                       const float4* __restrict__ cam,
                                                       float* __restrict__ out) {
    __shared__ float4 lds[4 * M_CAM];   // 128 KiB SoA camera table

    // One-time cooperative fill: linear copy (coalesced global, conflict-free LDS).
    for (int i = threadIdx.x; i < 4 * M_CAM; i += blockDim.x) {
        lds[i] = cam[i];
    }
    __syncthreads();

    const int stride = gridDim.x * blockDim.x;
    const float4* __restrict__ X4 = (const float4*)X;
    const int4* __restrict__ I4 = (const int4*)idx;
    float4* __restrict__ O4 = (float4*)out;

    int t = blockIdx.x * blockDim.x + threadIdx.x;
    if (t >= NG) return;

    // Software pipeline: prefetch next iteration's X/idx under current compute.
    float4 a = X4[3 * t + 0];
    float4 b = X4[3 * t + 1];
    float4 c = X4[3 * t + 2];
    int4 ci = I4[t];

    while (true) {
        int tn = t + stride;
        float4 na, nb, nc;
        int4 nci;
        bool more = tn < NG;
        if (more) {
            na = X4[3 * tn + 0];
            nb = X4[3 * tn + 1];
            nc = X4[3 * tn + 2];
            nci = I4[tn];
        }

        float2 uv0 = project_one(lds, ci.x, a.x, a.y, a.z);
        float2 uv1 = project_one(lds, ci.y, a.w, b.x, b.y);
        float2 uv2 = project_one(lds, ci.z, b.z, b.w, c.x);
        float2 uv3 = project_one(lds, ci.w, c.y, c.z, c.w);

        O4[2 * t + 0] = make_float4(uv0.x, uv0.y, uv1.x, uv1.y);
        O4[2 * t + 1] = make_float4(uv2.x, uv2.y, uv3.x, uv3.y);

        if (!more) break;
        t = tn; a = na; b = nb; c = nc; ci = nci;
    }
}

extern "C" void kernel_launch(void* const* d_in, const int* in_sizes, int n_in,
                              void* d_out, int out_size, void* d_ws, size_t ws_size,
                              hipStream_t stream) {
    const float* X_world      = (const float*)d_in[0];
    const int*   cam_idx      = (const int*)d_in[1];
    const float* intrinsics   = (const float*)d_in[2];
    const float* R_noisy      = (const float*)d_in[3];
    const float* t_noisy      = (const float*)d_in[4];
    const float* intr_deltas  = (const float*)d_in[5];
    const float* rot_deltas   = (const float*)d_in[6];
    const float* trans_deltas = (const float*)d_in[7];
    float* out = (float*)d_out;
    float4* cam = (float4*)d_ws;   // 4 * 2048 * 16 B = 128 KiB SoA table

    cam_precompute<<<(M_CAM + 255) / 256, 256, 0, stream>>>(
        intrinsics, R_noisy, t_noisy, intr_deltas, rot_deltas, trans_deltas, cam);

    // 256 blocks (1 per CU; 128 KiB LDS allows exactly 1 resident block/CU)
    // x 1024 threads -> 4 pipelined iterations of 4 points per thread.
    project_points<<<256, 1024, 0, stream>>>(X_world, cam_idx, cam, out);
}

// Round 3
// 27.305 us; speedup vs baseline: 2.2392x; 1.0350x over previous
//
#include <hip/hip_runtime.h>
#include <math.h>

#define N_PTS 4194304
#define M_CAM 2048
#define NG (N_PTS / 4)         // 1,048,576 groups of 4 points
#define THREADS 1024
#define BLOCKS 256
#define GSTRIDE (THREADS * BLOCKS)   // 262,144 threads; 4 groups per thread

// Fused single kernel:
//   Phase 1: every block builds the full camera table in its own LDS.
//     l0[c] = (fx*R00, fx*R01, fx*R02, fx*t0)
//     l1[c] = (fy*R10, fy*R11, fy*R12, fy*t1)
//     l2[c] = (R20,    R21,    R22,    t2)
//     lc[c] = (cx, cy)
//   Phase 2: grid-stride projection, all global loads issued up front.

__global__ __launch_bounds__(1024) void camera_project_fused(
        const float* __restrict__ X,
        const int* __restrict__ idx,
        const float* __restrict__ intr,
        const float* __restrict__ Rn,
        const float* __restrict__ tn,
        const float* __restrict__ intr_d,
        const float* __restrict__ rot_d,
        const float* __restrict__ trans_d,
        float* __restrict__ out) {
    __shared__ float4 l0[M_CAM];   // 32 KiB
    __shared__ float4 l1[M_CAM];   // 32 KiB
    __shared__ float4 l2[M_CAM];   // 32 KiB
    __shared__ float2 lc[M_CAM];   // 16 KiB  -> 112 KiB total

    const int tid = blockIdx.x * THREADS + threadIdx.x;
    const float4* __restrict__ X4 = (const float4*)X;
    const int4* __restrict__ I4 = (const int4*)idx;
    float4* __restrict__ O4 = (float4*)out;

    // ---- Issue ALL phase-2 global loads up front (fly under phase 1) ----
    const int g0 = tid;
    const int g1 = tid + GSTRIDE;
    const int g2 = tid + 2 * GSTRIDE;
    const int g3 = tid + 3 * GSTRIDE;

    float4 a0 = X4[3 * g0 + 0], b0 = X4[3 * g0 + 1], c0 = X4[3 * g0 + 2];
    float4 a1 = X4[3 * g1 + 0], b1 = X4[3 * g1 + 1], c1 = X4[3 * g1 + 2];
    float4 a2 = X4[3 * g2 + 0], b2 = X4[3 * g2 + 1], c2 = X4[3 * g2 + 2];
    float4 a3 = X4[3 * g3 + 0], b3 = X4[3 * g3 + 1], c3 = X4[3 * g3 + 2];
    int4 i0 = I4[g0], i1 = I4[g1], i2 = I4[g2], i3 = I4[g3];

    // ---- Phase 1: build camera table (2 cameras per thread) ----
    for (int m = threadIdx.x; m < M_CAM; m += THREADS) {
        float rx = rot_d[3 * m + 0];
        float ry = rot_d[3 * m + 1];
        float rz = rot_d[3 * m + 2];
        float theta = sqrtf(rx * rx + ry * ry + rz * rz);
        float inv = 1.0f / fmaxf(theta, 1e-12f);
        float kx = rx * inv, ky = ry * inv, kz = rz * inv;
        float st = sinf(theta);
        float ct = cosf(theta);
        float omc = 1.0f - ct;

        // R_delta = I + st*K + (1-ct)*K^2
        float Rd[9];
        Rd[0] = 1.0f - omc * (ky * ky + kz * kz);
        Rd[1] = -st * kz + omc * (kx * ky);
        Rd[2] =  st * ky + omc * (kx * kz);
        Rd[3] =  st * kz + omc * (kx * ky);
        Rd[4] = 1.0f - omc * (kx * kx + kz * kz);
        Rd[5] = -st * kx + omc * (ky * kz);
        Rd[6] = -st * ky + omc * (kx * kz);
        Rd[7] =  st * kx + omc * (ky * kz);
        Rd[8] = 1.0f - omc * (kx * kx + ky * ky);

        // R_corr = R_delta @ R_noisy
        float Rm[9];
#pragma unroll
        for (int i = 0; i < 3; ++i) {
#pragma unroll
            for (int j = 0; j < 3; ++j) {
                Rm[3 * i + j] = Rd[3 * i + 0] * Rn[9 * m + 0 + j]
                              + Rd[3 * i + 1] * Rn[9 * m + 3 + j]
                              + Rd[3 * i + 2] * Rn[9 * m + 6 + j];
            }
        }

        float t0 = tn[3 * m + 0] + trans_d[3 * m + 0];
        float t1 = tn[3 * m + 1] + trans_d[3 * m + 1];
        float t2 = tn[3 * m + 2] + trans_d[3 * m + 2];

        const float4* intr4 = (const float4*)intr;
        const float4* intrd4 = (const float4*)intr_d;
        float4 ki = intr4[m];
        float4 kd = intrd4[m];
        float fx = ki.x + kd.x;
        float fy = ki.y + kd.y;
        float cx = ki.z + kd.z;
        float cy = ki.w + kd.w;

        l0[m] = make_float4(fx * Rm[0], fx * Rm[1], fx * Rm[2], fx * t0);
        l1[m] = make_float4(fy * Rm[3], fy * Rm[4], fy * Rm[5], fy * t1);
        l2[m] = make_float4(Rm[6], Rm[7], Rm[8], t2);
        lc[m] = make_float2(cx, cy);
    }
    __syncthreads();

    // ---- Phase 2: project ----
    auto proj = [&](int c, float px, float py, float pz) -> float2 {
        float4 r0 = l0[c];
        float4 r1 = l1[c];
        float4 r2 = l2[c];
        float2 cc = lc[c];
        float nu = fmaf(r0.x, px, fmaf(r0.y, py, fmaf(r0.z, pz, r0.w)));
        float nv = fmaf(r1.x, px, fmaf(r1.y, py, fmaf(r1.z, pz, r1.w)));
        float zc = fmaf(r2.x, px, fmaf(r2.y, py, fmaf(r2.z, pz, r2.w)));
        float iz = 1.0f / zc;
        return make_float2(fmaf(nu, iz, cc.x), fmaf(nv, iz, cc.y));
    };

    {
        float2 u0 = proj(i0.x, a0.x, a0.y, a0.z);
        float2 u1 = proj(i0.y, a0.w, b0.x, b0.y);
        float2 u2 = proj(i0.z, b0.z, b0.w, c0.x);
        float2 u3 = proj(i0.w, c0.y, c0.z, c0.w);
        O4[2 * g0 + 0] = make_float4(u0.x, u0.y, u1.x, u1.y);
        O4[2 * g0 + 1] = make_float4(u2.x, u2.y, u3.x, u3.y);
    }
    {
        float2 u0 = proj(i1.x, a1.x, a1.y, a1.z);
        float2 u1 = proj(i1.y, a1.w, b1.x, b1.y);
        float2 u2 = proj(i1.z, b1.z, b1.w, c1.x);
        float2 u3 = proj(i1.w, c1.y, c1.z, c1.w);
        O4[2 * g1 + 0] = make_float4(u0.x, u0.y, u1.x, u1.y);
        O4[2 * g1 + 1] = make_float4(u2.x, u2.y, u3.x, u3.y);
    }
    {
        float2 u0 = proj(i2.x, a2.x, a2.y, a2.z);
        float2 u1 = proj(i2.y, a2.w, b2.x, b2.y);
        float2 u2 = proj(i2.z, b2.z, b2.w, c2.x);
        float2 u3 = proj(i2.w, c2.y, c2.z, c2.w);
        O4[2 * g2 + 0] = make_float4(u0.x, u0.y, u1.x, u1.y);
        O4[2 * g2 + 1] = make_float4(u2.x, u2.y, u3.x, u3.y);
    }
    {
        float2 u0 = proj(i3.x, a3.x, a3.y, a3.z);
        float2 u1 = proj(i3.y, a3.w, b3.x, b3.y);
        float2 u2 = proj(i3.z, b3.z, b3.w, c3.x);
        float2 u3 = proj(i3.w, c3.y, c3.z, c3.w);
        O4[2 * g3 + 0] = make_float4(u0.x, u0.y, u1.x, u1.y);
        O4[2 * g3 + 1] = make_float4(u2.x, u2.y, u3.x, u3.y);
    }
}

extern "C" void kernel_launch(void* const* d_in, const int* in_sizes, int n_in,
                              void* d_out, int out_size, void* d_ws, size_t ws_size,
                              hipStream_t stream) {
    const float* X_world      = (const float*)d_in[0];
    const int*   cam_idx      = (const int*)d_in[1];
    const float* intrinsics   = (const float*)d_in[2];
    const float* R_noisy      = (const float*)d_in[3];
    const float* t_noisy      = (const float*)d_in[4];
    const float* intr_deltas  = (const float*)d_in[5];
    const float* rot_deltas   = (const float*)d_in[6];
    const float* trans_deltas = (const float*)d_in[7];
    float* out = (float*)d_out;

    camera_project_fused<<<BLOCKS, THREADS, 0, stream>>>(
        X_world, cam_idx, intrinsics, R_noisy, t_noisy,
        intr_deltas, rot_deltas, trans_deltas, out);
}

// Round 4
// 22.483 us; speedup vs baseline: 2.7193x; 1.2144x over previous
//
#include <hip/hip_runtime.h>
#include <math.h>

#define N_PTS 4194304
#define M_CAM 2048
#define NG (N_PTS / 4)               // 1,048,576 groups of 4 points
#define THREADS 1024
#define BLOCKS 256
#define GSTRIDE (THREADS * BLOCKS)   // 262,144 threads; 4 groups per thread

// LDS camera table, 3 rows per camera (48 B):
//   l0[c] = (fx*R00+cx*R20, fx*R01+cx*R21, fx*R02+cx*R22, fx*t0+cx*t2)  -> u numerator
//   l1[c] = (fy*R10+cy*R20, fy*R11+cy*R21, fy*R12+cy*R22, fy*t1+cy*t2)  -> v numerator
//   l2[c] = (R20, R21, R22, t2)                                          -> z
// u = dot(l0[c],(p,1)) / z ; v = dot(l1[c],(p,1)) / z

__global__ __launch_bounds__(1024) void camera_project_fused(
        const float* __restrict__ X,
        const int* __restrict__ idx,
        const float* __restrict__ intr,
        const float* __restrict__ Rn,
        const float* __restrict__ tn,
        const float* __restrict__ intr_d,
        const float* __restrict__ rot_d,
        const float* __restrict__ trans_d,
        float* __restrict__ out) {
    __shared__ float4 l0[M_CAM];   // 32 KiB
    __shared__ float4 l1[M_CAM];   // 32 KiB
    __shared__ float4 l2[M_CAM];   // 32 KiB  -> 96 KiB total

    const int tid = blockIdx.x * THREADS + threadIdx.x;
    const float4* __restrict__ X4 = (const float4*)X;
    const int4* __restrict__ I4 = (const int4*)idx;
    float4* __restrict__ O4 = (float4*)out;

    // ---- Issue CAMERA loads first (phase 1 blocks on these) ----
    const int m0 = threadIdx.x;            // camera 0 of this thread
    const int m1 = threadIdx.x + THREADS;  // camera 1
    const float4* intr4 = (const float4*)intr;
    const float4* intrd4 = (const float4*)intr_d;

    float rd0x = rot_d[3 * m0 + 0], rd0y = rot_d[3 * m0 + 1], rd0z = rot_d[3 * m0 + 2];
    float rd1x = rot_d[3 * m1 + 0], rd1y = rot_d[3 * m1 + 1], rd1z = rot_d[3 * m1 + 2];
    float Rn0[9], Rn1[9];
#pragma unroll
    for (int j = 0; j < 9; ++j) Rn0[j] = Rn[9 * m0 + j];
#pragma unroll
    for (int j = 0; j < 9; ++j) Rn1[j] = Rn[9 * m1 + j];
    float tn0x = tn[3 * m0 + 0], tn0y = tn[3 * m0 + 1], tn0z = tn[3 * m0 + 2];
    float tn1x = tn[3 * m1 + 0], tn1y = tn[3 * m1 + 1], tn1z = tn[3 * m1 + 2];
    float td0x = trans_d[3 * m0 + 0], td0y = trans_d[3 * m0 + 1], td0z = trans_d[3 * m0 + 2];
    float td1x = trans_d[3 * m1 + 0], td1y = trans_d[3 * m1 + 1], td1z = trans_d[3 * m1 + 2];
    float4 ki0 = intr4[m0], kd0 = intrd4[m0];
    float4 ki1 = intr4[m1], kd1 = intrd4[m1];

    // ---- Prefetch group 0 of phase 2 (flies under phase-1 compute) ----
    const int g0 = tid;
    float4 cA = X4[3 * g0 + 0];
    float4 cB = X4[3 * g0 + 1];
    float4 cC = X4[3 * g0 + 2];
    int4 cI = I4[g0];

    // ---- Phase 1: build camera table (2 cameras per thread) ----
    auto build = [&](int m, float rx, float ry, float rz, const float* Rnl,
                     float tnx, float tny, float tnz,
                     float tdx, float tdy, float tdz, float4 ki, float4 kd) {
        float theta = sqrtf(rx * rx + ry * ry + rz * rz);
        float inv = 1.0f / fmaxf(theta, 1e-12f);
        float kx = rx * inv, ky = ry * inv, kz = rz * inv;
        float st = sinf(theta);
        float ct = cosf(theta);
        float omc = 1.0f - ct;

        float Rd[9];
        Rd[0] = 1.0f - omc * (ky * ky + kz * kz);
        Rd[1] = -st * kz + omc * (kx * ky);
        Rd[2] =  st * ky + omc * (kx * kz);
        Rd[3] =  st * kz + omc * (kx * ky);
        Rd[4] = 1.0f - omc * (kx * kx + kz * kz);
        Rd[5] = -st * kx + omc * (ky * kz);
        Rd[6] = -st * ky + omc * (kx * kz);
        Rd[7] =  st * kx + omc * (ky * kz);
        Rd[8] = 1.0f - omc * (kx * kx + ky * ky);

        float Rm[9];
#pragma unroll
        for (int i = 0; i < 3; ++i) {
#pragma unroll
            for (int j = 0; j < 3; ++j) {
                Rm[3 * i + j] = Rd[3 * i + 0] * Rnl[0 + j]
                              + Rd[3 * i + 1] * Rnl[3 + j]
                              + Rd[3 * i + 2] * Rnl[6 + j];
            }
        }

        float t0 = tnx + tdx, t1 = tny + tdy, t2 = tnz + tdz;
        float fx = ki.x + kd.x, fy = ki.y + kd.y;
        float cx = ki.z + kd.z, cy = ki.w + kd.w;

        l0[m] = make_float4(fmaf(fx, Rm[0], cx * Rm[6]),
                            fmaf(fx, Rm[1], cx * Rm[7]),
                            fmaf(fx, Rm[2], cx * Rm[8]),
                            fmaf(fx, t0, cx * t2));
        l1[m] = make_float4(fmaf(fy, Rm[3], cy * Rm[6]),
                            fmaf(fy, Rm[4], cy * Rm[7]),
                            fmaf(fy, Rm[5], cy * Rm[8]),
                            fmaf(fy, t1, cy * t2));
        l2[m] = make_float4(Rm[6], Rm[7], Rm[8], t2);
    };
    build(m0, rd0x, rd0y, rd0z, Rn0, tn0x, tn0y, tn0z, td0x, td0y, td0z, ki0, kd0);
    build(m1, rd1x, rd1y, rd1z, Rn1, tn1x, tn1y, tn1z, td1x, td1y, td1z, ki1, kd1);
    __syncthreads();

    // ---- Phase 2: rolling 2-stage pipeline over 4 groups ----
    auto proj = [&](int c, float px, float py, float pz) -> float2 {
        float4 r0 = l0[c];
        float4 r1 = l1[c];
        float4 r2 = l2[c];
        float nu = fmaf(r0.x, px, fmaf(r0.y, py, fmaf(r0.z, pz, r0.w)));
        float nv = fmaf(r1.x, px, fmaf(r1.y, py, fmaf(r1.z, pz, r1.w)));
        float zc = fmaf(r2.x, px, fmaf(r2.y, py, fmaf(r2.z, pz, r2.w)));
        float iz = 1.0f / zc;
        return make_float2(nu * iz, nv * iz);
    };
    auto process = [&](int g, float4 a, float4 b, float4 c, int4 ci) {
        float2 u0 = proj(ci.x, a.x, a.y, a.z);
        float2 u1 = proj(ci.y, a.w, b.x, b.y);
        float2 u2 = proj(ci.z, b.z, b.w, c.x);
        float2 u3 = proj(ci.w, c.y, c.z, c.w);
        O4[2 * g + 0] = make_float4(u0.x, u0.y, u1.x, u1.y);
        O4[2 * g + 1] = make_float4(u2.x, u2.y, u3.x, u3.y);
    };

    // stage 1 issue
    const int g1 = g0 + GSTRIDE;
    float4 nA = X4[3 * g1 + 0];
    float4 nB = X4[3 * g1 + 1];
    float4 nC = X4[3 * g1 + 2];
    int4 nI = I4[g1];

    process(g0, cA, cB, cC, cI);

    // stage 2 issue
    const int g2 = g0 + 2 * GSTRIDE;
    cA = X4[3 * g2 + 0];
    cB = X4[3 * g2 + 1];
    cC = X4[3 * g2 + 2];
    cI = I4[g2];

    process(g1, nA, nB, nC, nI);

    // stage 3 issue
    const int g3 = g0 + 3 * GSTRIDE;
    nA = X4[3 * g3 + 0];
    nB = X4[3 * g3 + 1];
    nC = X4[3 * g3 + 2];
    nI = I4[g3];

    process(g2, cA, cB, cC, cI);
    process(g3, nA, nB, nC, nI);
}

extern "C" void kernel_launch(void* const* d_in, const int* in_sizes, int n_in,
                              void* d_out, int out_size, void* d_ws, size_t ws_size,
                              hipStream_t stream) {
    const float* X_world      = (const float*)d_in[0];
    const int*   cam_idx      = (const int*)d_in[1];
    const float* intrinsics   = (const float*)d_in[2];
    const float* R_noisy      = (const float*)d_in[3];
    const float* t_noisy      = (const float*)d_in[4];
    const float* intr_deltas  = (const float*)d_in[5];
    const float* rot_deltas   = (const float*)d_in[6];
    const float* trans_deltas = (const float*)d_in[7];
    float* out = (float*)d_out;

    camera_project_fused<<<BLOCKS, THREADS, 0, stream>>>(
        X_world, cam_idx, intrinsics, R_noisy, t_noisy,
        intr_deltas, rot_deltas, trans_deltas, out);
}

// Round 5
// 22.399 us; speedup vs baseline: 2.7295x; 1.0038x over previous
//
#include <hip/hip_runtime.h>
#include <math.h>

#define N_PTS 4194304
#define M_CAM 2048
#define NG (N_PTS / 4)               // 1,048,576 groups of 4 points
#define THREADS 1024
#define BLOCKS 256
#define GSTRIDE (THREADS * BLOCKS)   // 262,144 threads; 4 groups per thread

// LDS camera table, 3 rows per camera (48 B):
//   l0[c] = (fx*R00+cx*R20, fx*R01+cx*R21, fx*R02+cx*R22, fx*t0+cx*t2)  -> u numerator
//   l1[c] = (fy*R10+cy*R20, fy*R11+cy*R21, fy*R12+cy*R22, fy*t1+cy*t2)  -> v numerator
//   l2[c] = (R20, R21, R22, t2)                                          -> z
// u = dot(l0[c],(p,1)) / z ; v = dot(l1[c],(p,1)) / z

__global__ __launch_bounds__(1024) void camera_project_fused(
        const float* __restrict__ X,
        const int* __restrict__ idx,
        const float* __restrict__ intr,
        const float* __restrict__ Rn,
        const float* __restrict__ tn,
        const float* __restrict__ intr_d,
        const float* __restrict__ rot_d,
        const float* __restrict__ trans_d,
        float* __restrict__ out) {
    __shared__ float4 l0[M_CAM];   // 32 KiB
    __shared__ float4 l1[M_CAM];   // 32 KiB
    __shared__ float4 l2[M_CAM];   // 32 KiB  -> 96 KiB total (1 block/CU)

    const int tid = blockIdx.x * THREADS + threadIdx.x;
    const float4* __restrict__ X4 = (const float4*)X;
    const int4* __restrict__ I4 = (const int4*)idx;
    float4* __restrict__ O4 = (float4*)out;

    // ---- Issue CAMERA loads first (build blocks on these; X loads queue behind) ----
    const int m0 = threadIdx.x;            // camera 0 of this thread
    const int m1 = threadIdx.x + THREADS;  // camera 1
    const float4* intr4 = (const float4*)intr;
    const float4* intrd4 = (const float4*)intr_d;

    float rd0x = rot_d[3 * m0 + 0], rd0y = rot_d[3 * m0 + 1], rd0z = rot_d[3 * m0 + 2];
    float rd1x = rot_d[3 * m1 + 0], rd1y = rot_d[3 * m1 + 1], rd1z = rot_d[3 * m1 + 2];
    float Rn0[9], Rn1[9];
#pragma unroll
    for (int j = 0; j < 9; ++j) Rn0[j] = Rn[9 * m0 + j];
#pragma unroll
    for (int j = 0; j < 9; ++j) Rn1[j] = Rn[9 * m1 + j];
    float tn0x = tn[3 * m0 + 0], tn0y = tn[3 * m0 + 1], tn0z = tn[3 * m0 + 2];
    float tn1x = tn[3 * m1 + 0], tn1y = tn[3 * m1 + 1], tn1z = tn[3 * m1 + 2];
    float td0x = trans_d[3 * m0 + 0], td0y = trans_d[3 * m0 + 1], td0z = trans_d[3 * m0 + 2];
    float td1x = trans_d[3 * m1 + 0], td1y = trans_d[3 * m1 + 1], td1z = trans_d[3 * m1 + 2];
    float4 ki0 = intr4[m0], kd0 = intrd4[m0];
    float4 ki1 = intr4[m1], kd1 = intrd4[m1];

    // ---- Prefetch groups 0 and 1 (fly under camera build; barrier drain lands them) ----
    const int g0 = tid;
    const int g1 = g0 + GSTRIDE;
    float4 A0 = X4[3 * g0 + 0], B0 = X4[3 * g0 + 1], C0 = X4[3 * g0 + 2];
    int4 I0 = I4[g0];
    float4 A1 = X4[3 * g1 + 0], B1 = X4[3 * g1 + 1], C1 = X4[3 * g1 + 2];
    int4 I1 = I4[g1];

    // ---- Phase 1: build camera table (2 cameras per thread) ----
    auto build = [&](int m, float rx, float ry, float rz, const float* Rnl,
                     float tnx, float tny, float tnz,
                     float tdx, float tdy, float tdz, float4 ki, float4 kd) {
        float theta = sqrtf(rx * rx + ry * ry + rz * rz);
        float inv = 1.0f / fmaxf(theta, 1e-12f);
        float kx = rx * inv, ky = ry * inv, kz = rz * inv;
        float st = sinf(theta);
        float ct = cosf(theta);
        float omc = 1.0f - ct;

        float Rd[9];
        Rd[0] = 1.0f - omc * (ky * ky + kz * kz);
        Rd[1] = -st * kz + omc * (kx * ky);
        Rd[2] =  st * ky + omc * (kx * kz);
        Rd[3] =  st * kz + omc * (kx * ky);
        Rd[4] = 1.0f - omc * (kx * kx + kz * kz);
        Rd[5] = -st * kx + omc * (ky * kz);
        Rd[6] = -st * ky + omc * (kx * kz);
        Rd[7] =  st * kx + omc * (ky * kz);
        Rd[8] = 1.0f - omc * (kx * kx + ky * ky);

        float Rm[9];
#pragma unroll
        for (int i = 0; i < 3; ++i) {
#pragma unroll
            for (int j = 0; j < 3; ++j) {
                Rm[3 * i + j] = Rd[3 * i + 0] * Rnl[0 + j]
                              + Rd[3 * i + 1] * Rnl[3 + j]
                              + Rd[3 * i + 2] * Rnl[6 + j];
            }
        }

        float t0 = tnx + tdx, t1 = tny + tdy, t2 = tnz + tdz;
        float fx = ki.x + kd.x, fy = ki.y + kd.y;
        float cx = ki.z + kd.z, cy = ki.w + kd.w;

        l0[m] = make_float4(fmaf(fx, Rm[0], cx * Rm[6]),
                            fmaf(fx, Rm[1], cx * Rm[7]),
                            fmaf(fx, Rm[2], cx * Rm[8]),
                            fmaf(fx, t0, cx * t2));
        l1[m] = make_float4(fmaf(fy, Rm[3], cy * Rm[6]),
                            fmaf(fy, Rm[4], cy * Rm[7]),
                            fmaf(fy, Rm[5], cy * Rm[8]),
                            fmaf(fy, t1, cy * t2));
        l2[m] = make_float4(Rm[6], Rm[7], Rm[8], t2);
    };
    build(m0, rd0x, rd0y, rd0z, Rn0, tn0x, tn0y, tn0z, td0x, td0y, td0z, ki0, kd0);
    build(m1, rd1x, rd1y, rd1z, Rn1, tn1x, tn1y, tn1z, td1x, td1y, td1z, ki1, kd1);
    __syncthreads();

    // ---- Phase 2: 2-deep prefetch pipeline over 4 groups ----
    auto proj = [&](int c, float px, float py, float pz) -> float2 {
        float4 r0 = l0[c];
        float4 r1 = l1[c];
        float4 r2 = l2[c];
        float nu = fmaf(r0.x, px, fmaf(r0.y, py, fmaf(r0.z, pz, r0.w)));
        float nv = fmaf(r1.x, px, fmaf(r1.y, py, fmaf(r1.z, pz, r1.w)));
        float zc = fmaf(r2.x, px, fmaf(r2.y, py, fmaf(r2.z, pz, r2.w)));
        float iz = 1.0f / zc;
        return make_float2(nu * iz, nv * iz);
    };
    auto process = [&](int g, float4 a, float4 b, float4 c, int4 ci) {
        float2 u0 = proj(ci.x, a.x, a.y, a.z);
        float2 u1 = proj(ci.y, a.w, b.x, b.y);
        float2 u2 = proj(ci.z, b.z, b.w, c.x);
        float2 u3 = proj(ci.w, c.y, c.z, c.w);
        O4[2 * g + 0] = make_float4(u0.x, u0.y, u1.x, u1.y);
        O4[2 * g + 1] = make_float4(u2.x, u2.y, u3.x, u3.y);
    };

    // Issue BOTH remaining groups now -> 2 groups (~106 KB/CU) in flight
    // while g0/g1 (already in registers after barrier drain) are processed.
    const int g2 = g0 + 2 * GSTRIDE;
    const int g3 = g0 + 3 * GSTRIDE;
    float4 A2 = X4[3 * g2 + 0], B2 = X4[3 * g2 + 1], C2 = X4[3 * g2 + 2];
    int4 I2 = I4[g2];
    float4 A3 = X4[3 * g3 + 0], B3 = X4[3 * g3 + 1], C3 = X4[3 * g3 + 2];
    int4 I3 = I4[g3];

    process(g0, A0, B0, C0, I0);
    process(g1, A1, B1, C1, I1);
    process(g2, A2, B2, C2, I2);
    process(g3, A3, B3, C3, I3);
}

extern "C" void kernel_launch(void* const* d_in, const int* in_sizes, int n_in,
                              void* d_out, int out_size, void* d_ws, size_t ws_size,
                              hipStream_t stream) {
    const float* X_world      = (const float*)d_in[0];
    const int*   cam_idx      = (const int*)d_in[1];
    const float* intrinsics   = (const float*)d_in[2];
    const float* R_noisy      = (const float*)d_in[3];
    const float* t_noisy      = (const float*)d_in[4];
    const float* intr_deltas  = (const float*)d_in[5];
    const float* rot_deltas   = (const float*)d_in[6];
    const float* trans_deltas = (const float*)d_in[7];
    float* out = (float*)d_out;

    camera_project_fused<<<BLOCKS, THREADS, 0, stream>>>(
        X_world, cam_idx, intrinsics, R_noisy, t_noisy,
        intr_deltas, rot_deltas, trans_deltas, out);
}

// Round 6
// 22.281 us; speedup vs baseline: 2.7441x; 1.0053x over previous
//
#include <hip/hip_runtime.h>
#include <math.h>

#define N_PTS 4194304
#define M_CAM 2048
#define NG (N_PTS / 4)               // 1,048,576 groups of 4 points
#define THREADS 1024
#define BLOCKS 256
#define GSTRIDE (THREADS * BLOCKS)   // 262,144 threads; 4 groups per thread

// LDS camera table, 3 rows per camera (48 B):
//   l0[c] = (fx*R00+cx*R20, fx*R01+cx*R21, fx*R02+cx*R22, fx*t0+cx*t2)  -> u numerator
//   l1[c] = (fy*R10+cy*R20, fy*R11+cy*R21, fy*R12+cy*R22, fy*t1+cy*t2)  -> v numerator
//   l2[c] = (R20, R21, R22, t2)                                          -> z
// u = dot(l0[c],(p,1)) / z ; v = dot(l1[c],(p,1)) / z

__global__ __launch_bounds__(1024) void camera_project_fused(
        const float* __restrict__ X,
        const int* __restrict__ idx,
        const float* __restrict__ intr,
        const float* __restrict__ Rn,
        const float* __restrict__ tn,
        const float* __restrict__ intr_d,
        const float* __restrict__ rot_d,
        const float* __restrict__ trans_d,
        float* __restrict__ out) {
    __shared__ float4 l0[M_CAM];   // 32 KiB
    __shared__ float4 l1[M_CAM];   // 32 KiB
    __shared__ float4 l2[M_CAM];   // 32 KiB  -> 96 KiB total (1 block/CU)

    const int tid = blockIdx.x * THREADS + threadIdx.x;
    const float4* __restrict__ X4 = (const float4*)X;
    const int4* __restrict__ I4 = (const int4*)idx;
    float4* __restrict__ O4 = (float4*)out;

    // ---- Issue CAMERA loads first (build blocks on these; X loads queue behind) ----
    const int m0 = threadIdx.x;            // camera 0 of this thread
    const int m1 = threadIdx.x + THREADS;  // camera 1
    const float4* intr4 = (const float4*)intr;
    const float4* intrd4 = (const float4*)intr_d;

    float rd0x = rot_d[3 * m0 + 0], rd0y = rot_d[3 * m0 + 1], rd0z = rot_d[3 * m0 + 2];
    float rd1x = rot_d[3 * m1 + 0], rd1y = rot_d[3 * m1 + 1], rd1z = rot_d[3 * m1 + 2];
    float Rn0[9], Rn1[9];
#pragma unroll
    for (int j = 0; j < 9; ++j) Rn0[j] = Rn[9 * m0 + j];
#pragma unroll
    for (int j = 0; j < 9; ++j) Rn1[j] = Rn[9 * m1 + j];
    float tn0x = tn[3 * m0 + 0], tn0y = tn[3 * m0 + 1], tn0z = tn[3 * m0 + 2];
    float tn1x = tn[3 * m1 + 0], tn1y = tn[3 * m1 + 1], tn1z = tn[3 * m1 + 2];
    float td0x = trans_d[3 * m0 + 0], td0y = trans_d[3 * m0 + 1], td0z = trans_d[3 * m0 + 2];
    float td1x = trans_d[3 * m1 + 0], td1y = trans_d[3 * m1 + 1], td1z = trans_d[3 * m1 + 2];
    float4 ki0 = intr4[m0], kd0 = intrd4[m0];
    float4 ki1 = intr4[m1], kd1 = intrd4[m1];

    // ---- Prefetch groups 0 and 1 (stay in flight ACROSS the barrier) ----
    const int g0 = tid;
    const int g1 = g0 + GSTRIDE;
    float4 A0 = X4[3 * g0 + 0], B0 = X4[3 * g0 + 1], C0 = X4[3 * g0 + 2];
    int4 I0 = I4[g0];
    float4 A1 = X4[3 * g1 + 0], B1 = X4[3 * g1 + 1], C1 = X4[3 * g1 + 2];
    int4 I1 = I4[g1];

    // ---- Phase 1: build camera table (2 cameras per thread) ----
    auto build = [&](int m, float rx, float ry, float rz, const float* Rnl,
                     float tnx, float tny, float tnz,
                     float tdx, float tdy, float tdz, float4 ki, float4 kd) {
        float theta = sqrtf(rx * rx + ry * ry + rz * rz);
        float inv = 1.0f / fmaxf(theta, 1e-12f);
        float kx = rx * inv, ky = ry * inv, kz = rz * inv;
        float st = sinf(theta);
        float ct = cosf(theta);
        float omc = 1.0f - ct;

        float Rd[9];
        Rd[0] = 1.0f - omc * (ky * ky + kz * kz);
        Rd[1] = -st * kz + omc * (kx * ky);
        Rd[2] =  st * ky + omc * (kx * kz);
        Rd[3] =  st * kz + omc * (kx * ky);
        Rd[4] = 1.0f - omc * (kx * kx + kz * kz);
        Rd[5] = -st * kx + omc * (ky * kz);
        Rd[6] = -st * ky + omc * (kx * kz);
        Rd[7] =  st * kx + omc * (ky * kz);
        Rd[8] = 1.0f - omc * (kx * kx + ky * ky);

        float Rm[9];
#pragma unroll
        for (int i = 0; i < 3; ++i) {
#pragma unroll
            for (int j = 0; j < 3; ++j) {
                Rm[3 * i + j] = Rd[3 * i + 0] * Rnl[0 + j]
                              + Rd[3 * i + 1] * Rnl[3 + j]
                              + Rd[3 * i + 2] * Rnl[6 + j];
            }
        }

        float t0 = tnx + tdx, t1 = tny + tdy, t2 = tnz + tdz;
        float fx = ki.x + kd.x, fy = ki.y + kd.y;
        float cx = ki.z + kd.z, cy = ki.w + kd.w;

        l0[m] = make_float4(fmaf(fx, Rm[0], cx * Rm[6]),
                            fmaf(fx, Rm[1], cx * Rm[7]),
                            fmaf(fx, Rm[2], cx * Rm[8]),
                            fmaf(fx, t0, cx * t2));
        l1[m] = make_float4(fmaf(fy, Rm[3], cy * Rm[6]),
                            fmaf(fy, Rm[4], cy * Rm[7]),
                            fmaf(fy, Rm[5], cy * Rm[8]),
                            fmaf(fy, t1, cy * t2));
        l2[m] = make_float4(Rm[6], Rm[7], Rm[8], t2);
    };
    build(m0, rd0x, rd0y, rd0z, Rn0, tn0x, tn0y, tn0z, td0x, td0y, td0z, ki0, kd0);
    build(m1, rd1x, rd1y, rd1z, Rn1, tn1x, tn1y, tn1z, td1x, td1y, td1z, ki1, kd1);

    // ---- Non-draining barrier: wait ONLY for LDS writes (lgkmcnt), not the
    //      in-flight global prefetches (vmcnt). The prefetched groups are
    //      wave-private register destinations -> no cross-wave hazard; the
    //      compiler inserts per-use vmcnt waits in process() below.
    asm volatile("s_waitcnt lgkmcnt(0)" ::: "memory");
    __builtin_amdgcn_s_barrier();
    __builtin_amdgcn_sched_barrier(0);

    // ---- Phase 2: 2-deep prefetch pipeline over 4 groups ----
    auto proj = [&](int c, float px, float py, float pz) -> float2 {
        float4 r0 = l0[c];
        float4 r1 = l1[c];
        float4 r2 = l2[c];
        float nu = fmaf(r0.x, px, fmaf(r0.y, py, fmaf(r0.z, pz, r0.w)));
        float nv = fmaf(r1.x, px, fmaf(r1.y, py, fmaf(r1.z, pz, r1.w)));
        float zc = fmaf(r2.x, px, fmaf(r2.y, py, fmaf(r2.z, pz, r2.w)));
        float iz = 1.0f / zc;
        return make_float2(nu * iz, nv * iz);
    };
    auto process = [&](int g, float4 a, float4 b, float4 c, int4 ci) {
        float2 u0 = proj(ci.x, a.x, a.y, a.z);
        float2 u1 = proj(ci.y, a.w, b.x, b.y);
        float2 u2 = proj(ci.z, b.z, b.w, c.x);
        float2 u3 = proj(ci.w, c.y, c.z, c.w);
        O4[2 * g + 0] = make_float4(u0.x, u0.y, u1.x, u1.y);
        O4[2 * g + 1] = make_float4(u2.x, u2.y, u3.x, u3.y);
    };

    // Issue both remaining groups now -> 2 groups in flight while g0/g1
    // (landing about now) are processed.
    const int g2 = g0 + 2 * GSTRIDE;
    const int g3 = g0 + 3 * GSTRIDE;
    float4 A2 = X4[3 * g2 + 0], B2 = X4[3 * g2 + 1], C2 = X4[3 * g2 + 2];
    int4 I2 = I4[g2];
    float4 A3 = X4[3 * g3 + 0], B3 = X4[3 * g3 + 1], C3 = X4[3 * g3 + 2];
    int4 I3 = I4[g3];

    process(g0, A0, B0, C0, I0);
    process(g1, A1, B1, C1, I1);
    process(g2, A2, B2, C2, I2);
    process(g3, A3, B3, C3, I3);
}

extern "C" void kernel_launch(void* const* d_in, const int* in_sizes, int n_in,
                              void* d_out, int out_size, void* d_ws, size_t ws_size,
                              hipStream_t stream) {
    const float* X_world      = (const float*)d_in[0];
    const int*   cam_idx      = (const int*)d_in[1];
    const float* intrinsics   = (const float*)d_in[2];
    const float* R_noisy      = (const float*)d_in[3];
    const float* t_noisy      = (const float*)d_in[4];
    const float* intr_deltas  = (const float*)d_in[5];
    const float* rot_deltas   = (const float*)d_in[6];
    const float* trans_deltas = (const float*)d_in[7];
    float* out = (float*)d_out;

    camera_project_fused<<<BLOCKS, THREADS, 0, stream>>>(
        X_world, cam_idx, intrinsics, R_noisy, t_noisy,
        intr_deltas, rot_deltas, trans_deltas, out);
}